// Round 3
// baseline (964.246 us; speedup 1.0000x reference)
//
#include <hip/hip_runtime.h>

// Problem constants: S=2048, N=8, E=512, C=1024, G=32, CG=32; rows R = S*N
#define ROWS 16384
#define EDIM 512
#define CDIM 1024

// d_out layout (fp32): [sampled (R*C) | softmax (R*C) | pos (R*E) | neg (R*E)]
#define OFF_SOFT (16384 * 1024)
#define OFF_POS  (2 * 16384 * 1024)
#define OFF_NEG  (2 * 16384 * 1024 + 16384 * 512)

// ---------------------------------------------------------------------------
// K0: transpose W2 (E x C) -> W2T (C x E) so gather-GEMM2 reads are coalesced
// ---------------------------------------------------------------------------
__global__ void transpose_w2_kernel(const float* __restrict__ in,
                                    float* __restrict__ out) {
  __shared__ float tile[32][33];
  const int bx = blockIdx.x * 32;  // c base
  const int by = blockIdx.y * 32;  // e base
  const int tx = threadIdx.x;
  const int ty = threadIdx.y;      // block (32, 8)
#pragma unroll
  for (int i = 0; i < 32; i += 8)
    tile[ty + i][tx] = in[(size_t)(by + ty + i) * CDIM + bx + tx];
  __syncthreads();
#pragma unroll
  for (int i = 0; i < 32; i += 8)
    out[(size_t)(bx + ty + i) * EDIM + by + tx] = tile[tx][ty + i];
}

// ---------------------------------------------------------------------------
// K1: fp32 SGEMM + FUSED softmax / Gumbel-argmax / sampled epilogue.
// logits[m,c] = 3*(sum_k x[m,k]*W1[c,k] + b1[c]) + coff[c]
// 128x128 tile, BK=16, 256 threads, 8x8 micro-tile.
// - Double-buffered LDS with register prefetch; ONE barrier per K-step
//   (writers touch buf^1 while readers compute on buf).
// - Bs stored with bank swizzle phys(c) = c + (c>>5)*4, row stride 140:
//   the 16 distinct read addresses cover all 32 banks exactly 2-way (free).
// Epilogue: each 4-thread cluster owns one 32-class group; 2x shfl_xor
// reductions. Writes softmax + sampled + 16B record (ci,cj,wa,wb) per group.
// ---------------------------------------------------------------------------
#define BM 128
#define BN 128
#define BK 16
#define TM 8
#define TN 8
#define BS_STRIDE 140  // 128 + swizzle headroom; 4*140 % 32 == 16 -> 2-way stores

__global__ __launch_bounds__(256, 4) void gemm1_fused_kernel(
    const float* __restrict__ A, const float* __restrict__ B,
    const float* __restrict__ bias1, const float* __restrict__ coff,
    const float* __restrict__ g1, const float* __restrict__ g2,
    const float* __restrict__ wI, const float* __restrict__ uI,
    float* __restrict__ out_samp, float* __restrict__ out_soft,
    float4* __restrict__ rec) {
  constexpr int K = EDIM;
  __shared__ __align__(16) float As[2][BK][BM + 4];      // stride 132
  __shared__ __align__(16) float Bs[2][BK][BS_STRIDE];
  const int bm = blockIdx.y * BM;
  const int bn = blockIdx.x * BN;
  const int tid = threadIdx.x;
  const int tx = tid & 15;
  const int ty = tid >> 4;

  float acc[TM][TN] = {};

  const int lrow = tid >> 2;       // 0..63
  const int lk4 = (tid & 3) << 2;  // 0,4,8,12

  // ---- prologue: stage k0=0 into buffer 0 ----
  {
#pragma unroll
    for (int i = 0; i < 2; i++) {
      const int row = lrow + i * 64;
      const float4 va = *(const float4*)&A[(size_t)(bm + row) * K + lk4];
      const float4 vb = *(const float4*)&B[(size_t)(bn + row) * K + lk4];
      As[0][lk4 + 0][row] = va.x;
      As[0][lk4 + 1][row] = va.y;
      As[0][lk4 + 2][row] = va.z;
      As[0][lk4 + 3][row] = va.w;
      const int pr = row + ((row >> 5) << 2);  // bank swizzle
      Bs[0][lk4 + 0][pr] = vb.x;
      Bs[0][lk4 + 1][pr] = vb.y;
      Bs[0][lk4 + 2][pr] = vb.z;
      Bs[0][lk4 + 3][pr] = vb.w;
    }
  }
  __syncthreads();

  const int bpc = tx * 8 + ((tx >> 2) << 2);  // swizzled Bs read offset
  int buf = 0;

  for (int k0 = 0; k0 < K - BK; k0 += BK) {
    // prefetch next tile into registers (global loads fly during compute)
    float4 pa[2], pb[2];
#pragma unroll
    for (int i = 0; i < 2; i++) {
      const int row = lrow + i * 64;
      pa[i] = *(const float4*)&A[(size_t)(bm + row) * K + k0 + BK + lk4];
      pb[i] = *(const float4*)&B[(size_t)(bn + row) * K + k0 + BK + lk4];
    }
    // compute on current buffer
#pragma unroll
    for (int k = 0; k < BK; k++) {
      const float4 a0 = *(const float4*)&As[buf][k][ty * TM];
      const float4 a1 = *(const float4*)&As[buf][k][ty * TM + 4];
      const float4 c0 = *(const float4*)&Bs[buf][k][bpc];
      const float4 c1 = *(const float4*)&Bs[buf][k][bpc + 4];
      const float a[8] = {a0.x, a0.y, a0.z, a0.w, a1.x, a1.y, a1.z, a1.w};
      const float b[8] = {c0.x, c0.y, c0.z, c0.w, c1.x, c1.y, c1.z, c1.w};
#pragma unroll
      for (int i = 0; i < TM; i++)
#pragma unroll
        for (int j = 0; j < TN; j++)
          acc[i][j] = fmaf(a[i], b[j], acc[i][j]);
    }
    // write prefetched tile into the other buffer (disjoint from readers)
    const int nb = buf ^ 1;
#pragma unroll
    for (int i = 0; i < 2; i++) {
      const int row = lrow + i * 64;
      As[nb][lk4 + 0][row] = pa[i].x;
      As[nb][lk4 + 1][row] = pa[i].y;
      As[nb][lk4 + 2][row] = pa[i].z;
      As[nb][lk4 + 3][row] = pa[i].w;
      const int pr = row + ((row >> 5) << 2);
      Bs[nb][lk4 + 0][pr] = pb[i].x;
      Bs[nb][lk4 + 1][pr] = pb[i].y;
      Bs[nb][lk4 + 2][pr] = pb[i].z;
      Bs[nb][lk4 + 3][pr] = pb[i].w;
    }
    __syncthreads();  // single barrier per K-step
    buf = nb;
  }
  // last tile
#pragma unroll
  for (int k = 0; k < BK; k++) {
    const float4 a0 = *(const float4*)&As[buf][k][ty * TM];
    const float4 a1 = *(const float4*)&As[buf][k][ty * TM + 4];
    const float4 c0 = *(const float4*)&Bs[buf][k][bpc];
    const float4 c1 = *(const float4*)&Bs[buf][k][bpc + 4];
    const float a[8] = {a0.x, a0.y, a0.z, a0.w, a1.x, a1.y, a1.z, a1.w};
    const float b[8] = {c0.x, c0.y, c0.z, c0.w, c1.x, c1.y, c1.z, c1.w};
#pragma unroll
    for (int i = 0; i < TM; i++)
#pragma unroll
      for (int j = 0; j < TN; j++)
        acc[i][j] = fmaf(a[i], b[j], acc[i][j]);
  }

  // ------------------- fused epilogue (unchanged arithmetic) -------------
  const int col0 = bn + tx * TN;
  const int cgbase = (tx & 3) * 8;
  const int g = (bn >> 5) + (tx >> 2);
  const float4 bias4a = *(const float4*)&bias1[col0];
  const float4 bias4b = *(const float4*)&bias1[col0 + 4];
  const float4 off4a = *(const float4*)&coff[col0];
  const float4 off4b = *(const float4*)&coff[col0 + 4];
  const float bb[8] = {bias4a.x, bias4a.y, bias4a.z, bias4a.w,
                       bias4b.x, bias4b.y, bias4b.z, bias4b.w};
  const float oo[8] = {off4a.x, off4a.y, off4a.z, off4a.w,
                       off4b.x, off4b.y, off4b.z, off4b.w};

#pragma unroll
  for (int i = 0; i < TM; i++) {
    const int row = bm + ty * TM + i;
    float lg[8];
#pragma unroll
    for (int j = 0; j < 8; j++) lg[j] = (acc[i][j] + bb[j]) * 3.0f + oo[j];

    float m = lg[0];
#pragma unroll
    for (int j = 1; j < 8; j++) m = fmaxf(m, lg[j]);
    m = fmaxf(m, __shfl_xor(m, 1));
    m = fmaxf(m, __shfl_xor(m, 2));

    float e[8], s = 0.0f;
#pragma unroll
    for (int j = 0; j < 8; j++) {
      e[j] = expf(lg[j] - m);
      s += e[j];
    }
    s += __shfl_xor(s, 1);
    s += __shfl_xor(s, 2);
    const float inv = 1.0f / s;
    const float lse = logf(s);

    const float* g1p = &g1[(size_t)row * CDIM + col0];
    const float* g2p = &g2[(size_t)row * CDIM + col0];
    const float4 gA0 = *(const float4*)g1p;
    const float4 gA1 = *(const float4*)(g1p + 4);
    const float4 gB0 = *(const float4*)g2p;
    const float4 gB1 = *(const float4*)(g2p + 4);
    const float ga[8] = {gA0.x, gA0.y, gA0.z, gA0.w, gA1.x, gA1.y, gA1.z, gA1.w};
    const float gb[8] = {gB0.x, gB0.y, gB0.z, gB0.w, gB1.x, gB1.y, gB1.z, gB1.w};

    float bv = (lg[0] - m) - lse + ga[0];
    int bi = cgbase;
    float cv = (lg[0] - m) - lse + gb[0];
    int cj = cgbase;
#pragma unroll
    for (int j = 1; j < 8; j++) {
      const float lp = (lg[j] - m) - lse;
      const float v1 = lp + ga[j];
      if (v1 > bv) { bv = v1; bi = cgbase + j; }
      const float v2 = lp + gb[j];
      if (v2 > cv) { cv = v2; cj = cgbase + j; }
    }
#pragma unroll
    for (int off = 1; off <= 2; off <<= 1) {
      const float ov = __shfl_xor(bv, off);
      const int oi = __shfl_xor(bi, off);
      if (ov > bv || (ov == bv && oi < bi)) { bv = ov; bi = oi; }
      const float ov2 = __shfl_xor(cv, off);
      const int oi2 = __shfl_xor(cj, off);
      if (ov2 > cv || (ov2 == cv && oi2 < cj)) { cv = ov2; cj = oi2; }
    }

    const float w = wI[(size_t)row * 32 + g];
    const float u = uI[(size_t)row * 32 + g];
    const bool take = (u < 1.0f);  // INTERP_PROB = 1.0

    float so[8], sa[8];
#pragma unroll
    for (int j = 0; j < 8; j++) {
      const float soft = e[j] * inv;
      const int cg = cgbase + j;
      const float interp =
          (cg == bi ? w : 0.0f) + (cg == cj ? 1.0f - w : 0.0f);
      const float oh = (cg == bi) ? 1.0f : 0.0f;
      const float hard = take ? interp : oh;
      so[j] = soft;
      sa[j] = soft + (hard - soft);
    }
    float* soft_p = &out_soft[(size_t)row * CDIM + col0];
    float* samp_p = &out_samp[(size_t)row * CDIM + col0];
    *(float4*)soft_p = make_float4(so[0], so[1], so[2], so[3]);
    *(float4*)(soft_p + 4) = make_float4(so[4], so[5], so[6], so[7]);
    *(float4*)samp_p = make_float4(sa[0], sa[1], sa[2], sa[3]);
    *(float4*)(samp_p + 4) = make_float4(sa[4], sa[5], sa[6], sa[7]);

    if ((tx & 3) == 0) {
      const float wa = take ? w : 1.0f;
      const float wb = take ? (1.0f - w) : 0.0f;
      rec[(size_t)row * 32 + g] =
          make_float4(__int_as_float(g * 32 + bi), __int_as_float(g * 32 + cj),
                      wa, wb);
    }
  }
}

// ---------------------------------------------------------------------------
// K2: one block per (s,n) row. Two 128-thread halves each gather 16 groups
// with float4 loads (W2T rows are L2-resident); partials combined via LDS;
// two-pass LayerNorm; writes pos and neg (identical forward values).
// ---------------------------------------------------------------------------
__global__ __launch_bounds__(256, 4) void finish_kernel(
    const float4* __restrict__ rec, const float* __restrict__ W2T,
    const float* __restrict__ b2, const float* __restrict__ gam,
    const float* __restrict__ bet, float* __restrict__ out_pos,
    float* __restrict__ out_neg) {
  const int r = blockIdx.x;
  const int tid = threadIdx.x;
  const int lane = tid & 63;
  const int wv = tid >> 6;
  const int h = tid >> 7;    // half-block id
  const int l = tid & 127;   // lane within half (float4 index into 512)

  __shared__ float s_wa[32], s_wb[32];
  __shared__ int s_ci[32], s_cj[32];
  __shared__ float4 s_part[128];
  __shared__ float s_red[4], s_red2[4];

  if (tid < 32) {
    const float4 f = rec[(size_t)r * 32 + tid];
    s_ci[tid] = __float_as_int(f.x);
    s_cj[tid] = __float_as_int(f.y);
    s_wa[tid] = f.z;
    s_wb[tid] = f.w;
  }
  __syncthreads();

  float4 a = make_float4(0.f, 0.f, 0.f, 0.f);
#pragma unroll 8
  for (int gi = 0; gi < 16; gi++) {
    const int g = h * 16 + gi;
    const float4 vi = ((const float4*)(W2T + (size_t)s_ci[g] * EDIM))[l];
    const float4 vj = ((const float4*)(W2T + (size_t)s_cj[g] * EDIM))[l];
    const float wa = s_wa[g], wb = s_wb[g];
    a.x += wa * vi.x + wb * vj.x;
    a.y += wa * vi.y + wb * vj.y;
    a.z += wa * vi.z + wb * vj.z;
    a.w += wa * vi.w + wb * vj.w;
  }
  if (h == 1) s_part[l] = a;
  __syncthreads();

  float4 hv = make_float4(0.f, 0.f, 0.f, 0.f);
  if (h == 0) {
    const float4 p = s_part[l];
    const float4 b2v = ((const float4*)b2)[l];
    hv.x = a.x + p.x + b2v.x;
    hv.y = a.y + p.y + b2v.y;
    hv.z = a.z + p.z + b2v.z;
    hv.w = a.w + p.w + b2v.w;
  }

  // mean (h==1 threads contribute 0)
  float ss = hv.x + hv.y + hv.z + hv.w;
#pragma unroll
  for (int off = 32; off >= 1; off >>= 1) ss += __shfl_xor(ss, off);
  if (lane == 0) s_red[wv] = ss;
  __syncthreads();
  const float mu = (s_red[0] + s_red[1] + s_red[2] + s_red[3]) * (1.0f / 512.0f);

  const float dx = hv.x - mu, dy = hv.y - mu, dz = hv.z - mu, dw = hv.w - mu;
  float vvv = (h == 0) ? (dx * dx + dy * dy + dz * dz + dw * dw) : 0.0f;
#pragma unroll
  for (int off = 32; off >= 1; off >>= 1) vvv += __shfl_xor(vvv, off);
  if (lane == 0) s_red2[wv] = vvv;
  __syncthreads();
  const float var =
      (s_red2[0] + s_red2[1] + s_red2[2] + s_red2[3]) * (1.0f / 512.0f);
  const float rsig = 1.0f / sqrtf(var + 1e-5f);

  if (h == 0) {
    const float4 gv = ((const float4*)gam)[l];
    const float4 bv = ((const float4*)bet)[l];
    float4 o;
    o.x = dx * rsig * gv.x + bv.x;
    o.y = dy * rsig * gv.y + bv.y;
    o.z = dz * rsig * gv.z + bv.z;
    o.w = dw * rsig * gv.w + bv.w;
    ((float4*)(out_pos + (size_t)r * EDIM))[l] = o;
    ((float4*)(out_neg + (size_t)r * EDIM))[l] = o;
  }
}

// ---------------------------------------------------------------------------
extern "C" void kernel_launch(void* const* d_in, const int* in_sizes, int n_in,
                              void* d_out, int out_size, void* d_ws,
                              size_t ws_size, hipStream_t stream) {
  const float* x = (const float*)d_in[0];
  const float* W1 = (const float*)d_in[1];
  const float* b1 = (const float*)d_in[2];
  const float* coff = (const float*)d_in[3];
  const float* W2 = (const float*)d_in[4];
  const float* b2 = (const float*)d_in[5];
  const float* gam = (const float*)d_in[6];
  const float* bet = (const float*)d_in[7];
  const float* g1 = (const float*)d_in[8];
  const float* g2 = (const float*)d_in[9];
  const float* wI = (const float*)d_in[10];
  const float* uI = (const float*)d_in[11];

  float* out = (float*)d_out;
  float* out_sampled = out;
  float* out_soft = out + OFF_SOFT;
  float* out_pos = out + OFF_POS;
  float* out_neg = out + OFF_NEG;

  float* W2T = (float*)d_ws;                                       // 2 MB
  float4* rec = (float4*)((char*)d_ws + (size_t)CDIM * EDIM * 4);  // 8 MB

  hipLaunchKernelGGL(transpose_w2_kernel, dim3(CDIM / 32, EDIM / 32),
                     dim3(32, 8), 0, stream, W2, W2T);
  hipLaunchKernelGGL(gemm1_fused_kernel, dim3(CDIM / BN, ROWS / BM), dim3(256),
                     0, stream, x, W1, b1, coff, g1, g2, wI, uI, out_sampled,
                     out_soft, rec);
  hipLaunchKernelGGL(finish_kernel, dim3(ROWS), dim3(256), 0, stream, rec, W2T,
                     b2, gam, bet, out_pos, out_neg);
}